// Round 9
// baseline (528.264 us; speedup 1.0000x reference)
//
#include <hip/hip_runtime.h>
#include <hip/hip_bf16.h>

// B=4, S=2048, E=1024, H=16, D=64
#define PB 4
#define PS 2048
#define PH 16
#define PD 64
#define PE 1024

typedef short v8s __attribute__((ext_vector_type(8)));
typedef float v4f __attribute__((ext_vector_type(4)));

// Q pre-scale: 1/sqrt(D) * log2(e), so softmax exp() becomes exp2()
#define QSCALE 0.18033688f

__device__ __forceinline__ ushort f2b(float f) {
  union { __hip_bfloat16 b; ushort u; } cv;
  cv.b = __float2bfloat16(f);
  return cv.u;
}

#if __has_builtin(__builtin_amdgcn_exp2f)
__device__ __forceinline__ float fexp2(float x) { return __builtin_amdgcn_exp2f(x); }
#else
__device__ __forceinline__ float fexp2(float x) { return exp2f(x); }
#endif

// async 16B global->LDS (direct DMA, no VGPR round trip) — used by GEMMs
__device__ __forceinline__ void cp16(const __hip_bfloat16* g, __hip_bfloat16* l) {
  __builtin_amdgcn_global_load_lds(
      (const __attribute__((address_space(1))) void*)g,
      (__attribute__((address_space(3))) void*)l, 16, 0, 0);
}

// XCD-aware bijective block remap (T1): consecutive remapped ids land on the
// SAME XCD in contiguous chunks, so blocks sharing operand panels hit the
// same L2. Requires nwg % 8 == 0 (all our grids: 1024 / 1536 / 512).
__device__ __forceinline__ int xcd_swz(int orig, int nwg) {
  return (orig & 7) * (nwg >> 3) + (orig >> 3);
}

// ---------------------------------------------------------------------------
// Prep kernels: fp32 -> bf16 convert / transpose (memory-bound)
// ---------------------------------------------------------------------------
__global__ __launch_bounds__(256) void conv_f2b(const float* __restrict__ S,
                                                __hip_bfloat16* __restrict__ D) {
  int i = blockIdx.x * 256 + threadIdx.x;
  float4 f = reinterpret_cast<const float4*>(S)[i];
  union { ushort u[4]; uint2 v; } pk;
  pk.u[0] = f2b(f.x); pk.u[1] = f2b(f.y); pk.u[2] = f2b(f.z); pk.u[3] = f2b(f.w);
  reinterpret_cast<uint2*>(D)[i] = pk.v;
}

// S [R][C] fp32 -> D [C][R] bf16
__global__ __launch_bounds__(256) void transp_f2b(const float* __restrict__ S,
                                                  __hip_bfloat16* __restrict__ D,
                                                  int R, int C) {
  __shared__ float tile[32][33];
  const int t = threadIdx.x;
  const int tx = t & 31, ty = t >> 5;
  const int r0 = blockIdx.y * 32, c0 = blockIdx.x * 32;
#pragma unroll
  for (int i = 0; i < 4; ++i)
    tile[ty + 8 * i][tx] = S[(size_t)(r0 + ty + 8 * i) * C + c0 + tx];
  __syncthreads();
#pragma unroll
  for (int i = 0; i < 4; ++i)
    D[(size_t)(c0 + ty + 8 * i) * R + r0 + tx] = __float2bfloat16(tile[tx][ty + 8 * i]);
}

// ---------------------------------------------------------------------------
// MFMA GEMM, BK=64, XOR-swizzled LDS, global_load_lds width-16 staging.
// 128x128 tile, 4 waves x (64x64). MODE 0: QKV scatter; MODE 1: proj fp32.
// XCD-swizzled block ids (verified R7: FETCH drop, L2 locality).
// ---------------------------------------------------------------------------
template <int MODE>
__global__ __launch_bounds__(256) void gemm_bt(
    const __hip_bfloat16* __restrict__ A, const __hip_bfloat16* __restrict__ BT,
    const float* __restrict__ bias, void* __restrict__ outv) {
  __shared__ __hip_bfloat16 As[128 * 64];
  __shared__ __hip_bfloat16 Bs[128 * 64];
  const int t = threadIdx.x;
  const int lane = t & 63, w = t >> 6;
  const int ln = lane & 15, qd = lane >> 4;
  const int wm = w >> 1, wn = w & 1;
  const int gx = gridDim.x;
  const int swz = xcd_swz(blockIdx.y * gx + blockIdx.x, gx * gridDim.y);
  const int m0 = (swz / gx) * 128, n0 = (swz % gx) * 128;
  v4f acc[4][4] = {};

  for (int k0 = 0; k0 < PE; k0 += 64) {
    __syncthreads();
#pragma unroll
    for (int i = 0; i < 4; ++i) {
      int idx = t + 256 * i;           // 0..1023 16B slots
      int r = idx >> 3, cs = idx & 7;  // 8 chunks per 64-elem row
      int cg = cs ^ (r & 7);
      cp16(A + (size_t)(m0 + r) * PE + k0 + cg * 8, As + idx * 8);
      cp16(BT + (size_t)(n0 + r) * PE + k0 + cg * 8, Bs + idx * 8);
    }
    __syncthreads();
#pragma unroll
    for (int kk = 0; kk < 2; ++kk) {
      v8s af[4], bf[4];
#pragma unroll
      for (int mb = 0; mb < 4; ++mb) {
        int ra = wm * 64 + mb * 16 + ln;
        int ca = (kk * 4 + qd) ^ (ra & 7);
        af[mb] = *reinterpret_cast<const v8s*>(As + ra * 64 + ca * 8);
      }
#pragma unroll
      for (int nb = 0; nb < 4; ++nb) {
        int rb = wn * 64 + nb * 16 + ln;
        int cb = (kk * 4 + qd) ^ (rb & 7);
        bf[nb] = *reinterpret_cast<const v8s*>(Bs + rb * 64 + cb * 8);
      }
#pragma unroll
      for (int mb = 0; mb < 4; ++mb)
#pragma unroll
        for (int nb = 0; nb < 4; ++nb)
          acc[mb][nb] = __builtin_amdgcn_mfma_f32_16x16x32_bf16(af[mb], bf[nb],
                                                                acc[mb][nb], 0, 0, 0);
    }
  }

  const int mwb = m0 + wm * 64 + qd * 4;
  const int nwb = n0 + wn * 64 + ln;
  if (MODE == 0) {
    __hip_bfloat16* QKV = (__hip_bfloat16*)outv;
#pragma unroll
    for (int nb = 0; nb < 4; ++nb) {
      int n = nwb + nb * 16;
      float bv = bias[n];
      int which = n >> 10, h = (n >> 6) & 15, d = n & 63;
#pragma unroll
      for (int mb = 0; mb < 4; ++mb) {
        int r0 = mwb + mb * 16;
        int b = r0 >> 11, s0 = r0 & (PS - 1);
        v4f a = acc[mb][nb];
        if (which == 2) {
          union { ushort u[4]; uint2 v; } pk;
#pragma unroll
          for (int i = 0; i < 4; ++i) pk.u[i] = f2b(a[i] + bv);
          size_t idx = (((size_t)(2 * PB + b) * PH + h) * PD + d) * PS + s0;
          *reinterpret_cast<uint2*>(&QKV[idx]) = pk.v;
        } else {
          float sc = (which == 0) ? QSCALE : 1.0f;
          size_t base = (((size_t)(which * PB + b) * PH + h) * PS + s0) * PD + d;
#pragma unroll
          for (int i = 0; i < 4; ++i)
            QKV[base + (size_t)i * PD] = __float2bfloat16((a[i] + bv) * sc);
        }
      }
    }
  } else {
    float* Co = (float*)outv;
#pragma unroll
    for (int nb = 0; nb < 4; ++nb) {
      int n = nwb + nb * 16;
      float bv = bias[n];
#pragma unroll
      for (int mb = 0; mb < 4; ++mb) {
        int r0 = mwb + mb * 16;
        v4f a = acc[mb][nb];
#pragma unroll
        for (int i = 0; i < 4; ++i)
          Co[(size_t)(r0 + i) * PE + n] = a[i] + bv;
      }
    }
  }
}

// ---------------------------------------------------------------------------
// MFMA flash attention v12: LDS-FREE. R8 arithmetic: v8's DS pipe was at
// ~100% (16 b128 writes + 32 b128 + 64 b64 reads per block-tile ≈ 2560 cy
// vs 2048-cy tile epoch) — the fixed point of v4..v11. K/V tiles are L2/L1
// resident (R7: FETCH 24MB, HBM 5%), and the MFMA fragment layouts map to
// clean global addresses:
//   K A-frag: 16B at Kb[key*64 + qd*8] (k1 at +32) — 64B-coalesced per key
//   V B-frag: 8B at Vb[d*PS + kt + 32s + qd*4] (second half at +16)
// So load fragments DIRECTLY from global: no LDS, no barriers, no staging.
// Waves are fully independent; 16 resident waves/CU cover L2 latency.
// Register-resident P (verified mapping), XCD swizzle for K/V L2 locality.
// QKV bf16: Q/K [b,h,s,d], V [b,h,d,s]. O bf16 [b,s,h,d]. Q pre-scaled.
// ---------------------------------------------------------------------------
__global__ __launch_bounds__(256) void attn_mfma12(
    const __hip_bfloat16* __restrict__ QKV, __hip_bfloat16* __restrict__ O) {
  const int t = threadIdx.x;
  const int lane = t & 63, w = t >> 6;
  const int ln = lane & 15, qd = lane >> 4;
  const int swz = xcd_swz(blockIdx.y * 16 + blockIdx.x, 16 * 64);
  const int bx = swz & 15, by = swz >> 4;
  const int b = by >> 4, h = by & 15;
  const int q0 = bx * 128;
  const __hip_bfloat16* Qb = QKV + (size_t)(b * PH + h) * PS * PD;
  const __hip_bfloat16* Kb = QKV + (size_t)((PB + b) * PH + h) * PS * PD;
  const __hip_bfloat16* Vb = QKV + (size_t)((2 * PB + b) * PH + h) * PD * PS;

  // Q B-frags: wave w owns q-rows q0+32w .. +31 (two 16-row sub-blocks u)
  v8s qf[2][2];
#pragma unroll
  for (int u = 0; u < 2; ++u) {
    size_t qr = (size_t)(q0 + 32 * w + 16 * u + ln) * PD;
    qf[u][0] = *reinterpret_cast<const v8s*>(Qb + qr + qd * 8);
    qf[u][1] = *reinterpret_cast<const v8s*>(Qb + qr + 32 + qd * 8);
  }
  v4f oacc[2][4] = {};
  float lrow[2] = {0.f, 0.f};

  // per-lane fragment base pointers (kt = 0)
  const __hip_bfloat16* kp = Kb + (size_t)ln * PD + qd * 8;  // + key16*PD, k1 +32
  const __hip_bfloat16* vp = Vb + (size_t)ln * PS + qd * 4;  // + d16*PS + kt + 32s

#pragma unroll 1
  for (int kt = 0; kt < PS; kt += 64) {
    // K fragments for this 64-key tile (8 x global_load_dwordx4, L2-hit)
    v8s kf0[4], kf1[4];
#pragma unroll
    for (int nb = 0; nb < 4; ++nb) {
      const __hip_bfloat16* kr = kp + (size_t)(kt + nb * 16) * PD;
      kf0[nb] = *reinterpret_cast<const v8s*>(kr);
      kf1[nb] = *reinterpret_cast<const v8s*>(kr + 32);
    }
    // S^T = K Q^T per sub-block; exp2; pack P into registers (pw)
    uint2 pw[2][4];
#pragma unroll
    for (int u = 0; u < 2; ++u) {
      float psum = 0.f;
#pragma unroll
      for (int nb = 0; nb < 4; ++nb) {
        v4f z = {};
        z = __builtin_amdgcn_mfma_f32_16x16x32_bf16(kf0[nb], qf[u][0], z, 0, 0, 0);
        v4f sv = __builtin_amdgcn_mfma_f32_16x16x32_bf16(kf1[nb], qf[u][1], z, 0, 0, 0);
        // lane holds keys nb*16+qd*4+i of q = 32w+16u+ln
        union { ushort pu[4]; uint2 pv; } pk;
#pragma unroll
        for (int i = 0; i < 4; ++i) {
          float p = fexp2(sv[i]);
          psum += p;
          pk.pu[i] = f2b(p);
        }
        pw[u][nb] = pk.pv;
      }
      // reduce over qd lane-groups (lane bits 4,5)
      psum += __shfl_xor(psum, 16);
      psum += __shfl_xor(psum, 32);
      lrow[u] += psum;
    }
    // O += P V, P direct from registers with permuted key order:
    // k-slot qd*8+j <-> key (2s+(j>>2))*16 + qd*4 + (j&3); V-frags loaded
    // straight from global (16 x dwordx2, L2-hit, 32B segments per d-row).
#pragma unroll
    for (int s = 0; s < 2; ++s) {
      union { v8s v; uint2 u2[2]; } a0, a1;
      a0.u2[0] = pw[0][2 * s]; a0.u2[1] = pw[0][2 * s + 1];
      a1.u2[0] = pw[1][2 * s]; a1.u2[1] = pw[1][2 * s + 1];
      __builtin_amdgcn_s_setprio(1);
#pragma unroll
      for (int db = 0; db < 4; ++db) {
        const __hip_bfloat16* vr = vp + (size_t)(db * 16) * PS + kt + s * 32;
        union { v8s v; uint2 u2[2]; } vf;
        vf.u2[0] = *reinterpret_cast<const uint2*>(vr);
        vf.u2[1] = *reinterpret_cast<const uint2*>(vr + 16);
        oacc[0][db] = __builtin_amdgcn_mfma_f32_16x16x32_bf16(a0.v, vf.v,
                                                              oacc[0][db], 0, 0, 0);
        oacc[1][db] = __builtin_amdgcn_mfma_f32_16x16x32_bf16(a1.v, vf.v,
                                                              oacc[1][db], 0, 0, 0);
      }
      __builtin_amdgcn_s_setprio(0);
    }
  }

  // epilogue: redistribute lrow (indexed by q=ln) to O C-layout (q=qd*4+i)
#pragma unroll
  for (int u = 0; u < 2; ++u) {
#pragma unroll
    for (int i = 0; i < 4; ++i) {
      float inv = 1.f / __shfl(lrow[u], qd * 4 + i);
      int sg = q0 + 32 * w + 16 * u + qd * 4 + i;
      size_t base = (((size_t)b * PS + sg) * PH + h) * PD;
#pragma unroll
      for (int db = 0; db < 4; ++db)
        O[base + db * 16 + ln] = __float2bfloat16(oacc[u][db][i] * inv);
    }
  }
}

// ---------------------------------------------------------------------------
// Legacy fp32-input GEMM (small-ws fallback)
// ---------------------------------------------------------------------------
__device__ __forceinline__ uint2 load4bf(const float* p) {
  const float4 f = *reinterpret_cast<const float4*>(p);
  union { ushort u[4]; uint2 v; } pk;
  pk.u[0] = f2b(f.x); pk.u[1] = f2b(f.y); pk.u[2] = f2b(f.z); pk.u[3] = f2b(f.w);
  return pk.v;
}
__device__ __forceinline__ uint2 load4bf(const __hip_bfloat16* p) {
  return *reinterpret_cast<const uint2*>(p);
}

template <typename AT, int MODE>
__global__ __launch_bounds__(256) void gemm128(
    const AT* __restrict__ A, const float* __restrict__ Bm,
    const float* __restrict__ bias, void* __restrict__ outv, int ldb) {
  __shared__ __hip_bfloat16 As[128][40];
  __shared__ __hip_bfloat16 Bs[128][40];
  const int t = threadIdx.x;
  const int lane = t & 63, w = t >> 6;
  const int ln = lane & 15, qd = lane >> 4;
  const int wm = w >> 1, wn = w & 1;
  const int m0 = blockIdx.y * 128, n0 = blockIdx.x * 128;
  v4f acc[4][4] = {};
  for (int k0 = 0; k0 < PE; k0 += 32) {
    __syncthreads();
#pragma unroll
    for (int i = 0; i < 4; ++i) {
      int p = t + 256 * i;
      int m = p >> 3, kc = p & 7;
      *reinterpret_cast<uint2*>(&As[m][kc * 4]) =
          load4bf(A + (size_t)(m0 + m) * PE + k0 + kc * 4);
    }
#pragma unroll
    for (int i = 0; i < 4; ++i) {
      int p = t + 256 * i;
      int n = p & 127, kc = p >> 7;
      union { ushort u[4]; uint2 v; } pk;
#pragma unroll
      for (int r = 0; r < 4; ++r)
        pk.u[r] = f2b(Bm[(size_t)(k0 + kc * 4 + r) * ldb + n0 + n]);
      *reinterpret_cast<uint2*>(&Bs[n][kc * 4]) = pk.v;
    }
    __syncthreads();
    v8s af[4], bf[4];
#pragma unroll
    for (int mb = 0; mb < 4; ++mb)
      af[mb] = *reinterpret_cast<const v8s*>(&As[wm * 64 + mb * 16 + ln][qd * 8]);
#pragma unroll
    for (int nb = 0; nb < 4; ++nb)
      bf[nb] = *reinterpret_cast<const v8s*>(&Bs[wn * 64 + nb * 16 + ln][qd * 8]);
#pragma unroll
    for (int mb = 0; mb < 4; ++mb)
#pragma unroll
      for (int nb = 0; nb < 4; ++nb)
        acc[mb][nb] = __builtin_amdgcn_mfma_f32_16x16x32_bf16(af[mb], bf[nb],
                                                              acc[mb][nb], 0, 0, 0);
  }
  const int mwb = m0 + wm * 64 + qd * 4;
  const int nwb = n0 + wn * 64 + ln;
  if (MODE == 0) {
    __hip_bfloat16* QKV = (__hip_bfloat16*)outv;
#pragma unroll
    for (int nb = 0; nb < 4; ++nb) {
      int n = nwb + nb * 16;
      float bv = bias[n];
      int which = n >> 10, h = (n >> 6) & 15, d = n & 63;
#pragma unroll
      for (int mb = 0; mb < 4; ++mb) {
        int r0 = mwb + mb * 16;
        int b = r0 >> 11, s0 = r0 & (PS - 1);
        v4f a = acc[mb][nb];
        if (which == 2) {
          union { ushort u[4]; uint2 v; } pk;
#pragma unroll
          for (int i = 0; i < 4; ++i) pk.u[i] = f2b(a[i] + bv);
          size_t idx = (((size_t)(2 * PB + b) * PH + h) * PD + d) * PS + s0;
          *reinterpret_cast<uint2*>(&QKV[idx]) = pk.v;
        } else {
          float sc = (which == 0) ? QSCALE : 1.0f;
          size_t base = (((size_t)(which * PB + b) * PH + h) * PS + s0) * PD + d;
#pragma unroll
          for (int i = 0; i < 4; ++i)
            QKV[base + (size_t)i * PD] = __float2bfloat16((a[i] + bv) * sc);
        }
      }
    }
  } else {
    float* Co = (float*)outv;
#pragma unroll
    for (int nb = 0; nb < 4; ++nb) {
      int n = nwb + nb * 16;
      float bv = bias[n];
#pragma unroll
      for (int mb = 0; mb < 4; ++mb) {
        int r0 = mwb + mb * 16;
        v4f a = acc[mb][nb];
#pragma unroll
        for (int i = 0; i < 4; ++i)
          Co[(size_t)(r0 + i) * PE + n] = a[i] + bv;
      }
    }
  }
}

// ---------------------------------------------------------------------------
extern "C" void kernel_launch(void* const* d_in, const int* in_sizes, int n_in,
                              void* d_out, int out_size, void* d_ws,
                              size_t ws_size, hipStream_t stream) {
  const float* x = (const float*)d_in[0];
  const float* w_qkv = (const float*)d_in[1];
  const float* b_qkv = (const float*)d_in[2];
  const float* w_proj = (const float*)d_in[3];
  const float* b_proj = (const float*)d_in[4];
  float* out = (float*)d_out;

  const size_t xE = (size_t)PB * PS * PE;             // 8,388,608
  const size_t wqE = (size_t)PE * 3 * PE;             // 3,145,728
  const size_t wpE = (size_t)PE * PE;                 // 1,048,576
  const size_t qkvE = (size_t)3 * PB * PH * PS * PD;  // 25,165,824
  const size_t needMain = (xE + wqE + wpE + qkvE) * 2;  // 75,497,472 B

  dim3 blk(256);
  dim3 gq(24, 64), ga(16, 64), gp(8, 64);

  if (ws_size >= needMain) {
    __hip_bfloat16* xb = (__hip_bfloat16*)d_ws;
    __hip_bfloat16* wqkvT = xb + xE;
    __hip_bfloat16* wprojT = wqkvT + wqE;
    __hip_bfloat16* qkv = wprojT + wpE;
    __hip_bfloat16* o = xb;  // xb dead after qkv gemm

    conv_f2b<<<dim3(xE / 1024), blk, 0, stream>>>(x, xb);
    transp_f2b<<<dim3(96, 32), blk, 0, stream>>>(w_qkv, wqkvT, PE, 3 * PE);
    transp_f2b<<<dim3(32, 32), blk, 0, stream>>>(w_proj, wprojT, PE, PE);
    gemm_bt<0><<<gq, blk, 0, stream>>>(xb, wqkvT, b_qkv, qkv);
    attn_mfma12<<<ga, blk, 0, stream>>>(qkv, o);
    gemm_bt<1><<<gp, blk, 0, stream>>>(o, wprojT, b_proj, out);
  } else {
    // legacy small-ws path
    __hip_bfloat16* qkv = (__hip_bfloat16*)d_ws;
    if (ws_size >= (qkvE + xE) * 2) {
      __hip_bfloat16* o = qkv + qkvE;
      gemm128<float, 0><<<gq, blk, 0, stream>>>(x, w_qkv, b_qkv, qkv, 3 * PE);
      attn_mfma12<<<ga, blk, 0, stream>>>(qkv, o);
      gemm128<__hip_bfloat16, 1><<<gp, blk, 0, stream>>>(o, w_proj, b_proj, out, PE);
    } else {
      __hip_bfloat16* o = (__hip_bfloat16*)d_out;
      float* tmp = (float*)d_ws;
      gemm128<float, 0><<<gq, blk, 0, stream>>>(x, w_qkv, b_qkv, qkv, 3 * PE);
      attn_mfma12<<<ga, blk, 0, stream>>>(qkv, o);
      gemm128<__hip_bfloat16, 1><<<gp, blk, 0, stream>>>(o, w_proj, b_proj, tmp, PE);
      hipMemcpyAsync(d_out, tmp, xE * sizeof(float), hipMemcpyDeviceToDevice, stream);
    }
  }
}

// Round 10
// 296.495 us; speedup vs baseline: 1.7817x; 1.7817x over previous
//
#include <hip/hip_runtime.h>
#include <hip/hip_bf16.h>

// B=4, S=2048, E=1024, H=16, D=64
#define PB 4
#define PS 2048
#define PH 16
#define PD 64
#define PE 1024

typedef short v8s __attribute__((ext_vector_type(8)));
typedef float v4f __attribute__((ext_vector_type(4)));

// Q pre-scale: 1/sqrt(D) * log2(e), so softmax exp() becomes exp2()
#define QSCALE 0.18033688f

__device__ __forceinline__ ushort f2b(float f) {
  union { __hip_bfloat16 b; ushort u; } cv;
  cv.b = __float2bfloat16(f);
  return cv.u;
}

#if __has_builtin(__builtin_amdgcn_exp2f)
__device__ __forceinline__ float fexp2(float x) { return __builtin_amdgcn_exp2f(x); }
#else
__device__ __forceinline__ float fexp2(float x) { return exp2f(x); }
#endif

// async 16B global->LDS (direct DMA, no VGPR round trip)
__device__ __forceinline__ void cp16(const __hip_bfloat16* g, __hip_bfloat16* l) {
  __builtin_amdgcn_global_load_lds(
      (const __attribute__((address_space(1))) void*)g,
      (__attribute__((address_space(3))) void*)l, 16, 0, 0);
}

// raw barrier with compiler memory fences (no vmcnt/lgkmcnt drain — unlike
// __syncthreads, which drains the global_load_lds queue every time)
__device__ __forceinline__ void barrier_fence() {
  asm volatile("" ::: "memory");
  __builtin_amdgcn_s_barrier();
  asm volatile("" ::: "memory");
}

// XCD-aware bijective block remap (T1, verified R7: attn FETCH 139->24MB).
// Requires nwg % 8 == 0 (grids: 1024 / 384 / 512).
__device__ __forceinline__ int xcd_swz(int orig, int nwg) {
  return (orig & 7) * (nwg >> 3) + (orig >> 3);
}

// ---------------------------------------------------------------------------
// Prep kernels: fp32 -> bf16 convert / transpose (memory-bound)
// ---------------------------------------------------------------------------
__global__ __launch_bounds__(256) void conv_f2b(const float* __restrict__ S,
                                                __hip_bfloat16* __restrict__ D) {
  int i = blockIdx.x * 256 + threadIdx.x;
  float4 f = reinterpret_cast<const float4*>(S)[i];
  union { ushort u[4]; uint2 v; } pk;
  pk.u[0] = f2b(f.x); pk.u[1] = f2b(f.y); pk.u[2] = f2b(f.z); pk.u[3] = f2b(f.w);
  reinterpret_cast<uint2*>(D)[i] = pk.v;
}

// S [R][C] fp32 -> D [C][R] bf16
__global__ __launch_bounds__(256) void transp_f2b(const float* __restrict__ S,
                                                  __hip_bfloat16* __restrict__ D,
                                                  int R, int C) {
  __shared__ float tile[32][33];
  const int t = threadIdx.x;
  const int tx = t & 31, ty = t >> 5;
  const int r0 = blockIdx.y * 32, c0 = blockIdx.x * 32;
#pragma unroll
  for (int i = 0; i < 4; ++i)
    tile[ty + 8 * i][tx] = S[(size_t)(r0 + ty + 8 * i) * C + c0 + tx];
  __syncthreads();
#pragma unroll
  for (int i = 0; i < 4; ++i)
    D[(size_t)(c0 + ty + 8 * i) * R + r0 + tx] = __float2bfloat16(tile[tx][ty + 8 * i]);
}

// ---------------------------------------------------------------------------
// gemm256: 256x256-tile 8-phase MFMA GEMM (QKV projection, MODE-0 epilogue).
// Port of the verified 8-phase template (learn_hip m198/m201 class):
// 512 threads = 8 waves (2Mx4N), per-wave output 128x64 (acc[8][4]);
// BK=64, double-buffered 128KB LDS; per K-tile 4 phases, each phase =
// { 12 ds_read_b128 (this phase's frags) || 2 global_load_lds (next tile)
//   -> raw barrier -> 16 MFMA (setprio) -> raw barrier }.
// vmcnt(0)+barrier only at tile flips — the 8 prefetch loads have had
// >=3 phases (~1000cy) to land, so the drain is effectively free (T4).
// LDS addressing = same XOR-swizzle scheme already verified in gemm_bt.
// ---------------------------------------------------------------------------
__global__ __launch_bounds__(512) void gemm256(
    const __hip_bfloat16* __restrict__ A, const __hip_bfloat16* __restrict__ BT,
    const float* __restrict__ bias, __hip_bfloat16* __restrict__ QKV) {
  __shared__ __hip_bfloat16 As[2][256 * 64];
  __shared__ __hip_bfloat16 Bs[2][256 * 64];
  const int t = threadIdx.x;
  const int lane = t & 63, w = t >> 6;  // 8 waves
  const int ln = lane & 15, qd = lane >> 4;
  const int wr = w >> 2, wc = w & 3;    // 2 x 4 wave grid
  const int gx = gridDim.x;
  const int swz = xcd_swz(blockIdx.y * gx + blockIdx.x, gx * gridDim.y);
  const int m0 = (swz / gx) * 256, n0 = (swz % gx) * 256;
  v4f acc[8][4] = {};

  // phase-p staging: thread stages A chunk (t+p*512) and B chunk (t+p*512).
  // 2048 16B-chunks per operand per tile; source col XOR-swizzled, LDS dest
  // linear (global_load_lds constraint — same scheme as gemm_bt, verified).
  auto STAGE = [&](int buf, int k0, int p) {
    int idx = t + p * 512;  // 0..2047
    int r = idx >> 3, cs = idx & 7;
    int cg = cs ^ (r & 7);
    cp16(A + (size_t)(m0 + r) * PE + k0 + cg * 8, As[buf] + idx * 8);
    cp16(BT + (size_t)(n0 + r) * PE + k0 + cg * 8, Bs[buf] + idx * 8);
  };

  // prologue: stage tile 0 fully, drain, sync
#pragma unroll
  for (int p = 0; p < 4; ++p) STAGE(0, 0, p);
  asm volatile("s_waitcnt vmcnt(0)" ::: "memory");
  barrier_fence();

#pragma unroll 1
  for (int tl = 0; tl < 16; ++tl) {
    const int buf = tl & 1;
    const __hip_bfloat16* Ab = As[buf];
    const __hip_bfloat16* Bb = Bs[buf];
    const int k1 = (tl + 1) * 64;
#pragma unroll
    for (int p = 0; p < 4; ++p) {
      v8s af[2][2], bf[4][2];
#pragma unroll
      for (int m = 0; m < 2; ++m) {
        int ra = wr * 128 + (p * 2 + m) * 16 + ln;
#pragma unroll
        for (int kk = 0; kk < 2; ++kk) {
          int ca = (kk * 4 + qd) ^ (ra & 7);
          af[m][kk] = *reinterpret_cast<const v8s*>(Ab + ra * 64 + ca * 8);
        }
      }
#pragma unroll
      for (int nb = 0; nb < 4; ++nb) {
        int rb = wc * 64 + nb * 16 + ln;
#pragma unroll
        for (int kk = 0; kk < 2; ++kk) {
          int cb = (kk * 4 + qd) ^ (rb & 7);
          bf[nb][kk] = *reinterpret_cast<const v8s*>(Bb + rb * 64 + cb * 8);
        }
      }
      if (tl < 15) STAGE(buf ^ 1, k1, p);
      barrier_fence();
      __builtin_amdgcn_s_setprio(1);
#pragma unroll
      for (int kk = 0; kk < 2; ++kk)
#pragma unroll
        for (int m = 0; m < 2; ++m)
#pragma unroll
          for (int nb = 0; nb < 4; ++nb)
            acc[p * 2 + m][nb] = __builtin_amdgcn_mfma_f32_16x16x32_bf16(
                af[m][kk], bf[nb][kk], acc[p * 2 + m][nb], 0, 0, 0);
      __builtin_amdgcn_s_setprio(0);
      barrier_fence();
    }
    // tile flip: this wave's 8 prefetch DMAs must be complete before anyone
    // reads buf^1; they were issued across the 4 phases above.
    asm volatile("s_waitcnt vmcnt(0)" ::: "memory");
    barrier_fence();
  }

  // QKV scatter epilogue (identical scheme to gemm_bt MODE 0, mb range 8)
  const int mwb = m0 + wr * 128 + qd * 4;
  const int nwb = n0 + wc * 64 + ln;
#pragma unroll
  for (int nb = 0; nb < 4; ++nb) {
    int n = nwb + nb * 16;
    float bv = bias[n];
    int which = n >> 10, h = (n >> 6) & 15, d = n & 63;
#pragma unroll
    for (int mb = 0; mb < 8; ++mb) {
      int r0 = mwb + mb * 16;
      int b = r0 >> 11, s0 = r0 & (PS - 1);
      v4f a = acc[mb][nb];
      if (which == 2) {
        union { ushort u[4]; uint2 v; } pk;
#pragma unroll
        for (int i = 0; i < 4; ++i) pk.u[i] = f2b(a[i] + bv);
        size_t idx = (((size_t)(2 * PB + b) * PH + h) * PD + d) * PS + s0;
        *reinterpret_cast<uint2*>(&QKV[idx]) = pk.v;
      } else {
        float sc = (which == 0) ? QSCALE : 1.0f;
        size_t base = (((size_t)(which * PB + b) * PH + h) * PS + s0) * PD + d;
#pragma unroll
        for (int i = 0; i < 4; ++i)
          QKV[base + (size_t)i * PD] = __float2bfloat16((a[i] + bv) * sc);
      }
    }
  }
}

// ---------------------------------------------------------------------------
// MFMA GEMM 128x128 (proj, MODE 1), BK=64, XOR-swizzled LDS, verified.
// ---------------------------------------------------------------------------
template <int MODE>
__global__ __launch_bounds__(256) void gemm_bt(
    const __hip_bfloat16* __restrict__ A, const __hip_bfloat16* __restrict__ BT,
    const float* __restrict__ bias, void* __restrict__ outv) {
  __shared__ __hip_bfloat16 As[128 * 64];
  __shared__ __hip_bfloat16 Bs[128 * 64];
  const int t = threadIdx.x;
  const int lane = t & 63, w = t >> 6;
  const int ln = lane & 15, qd = lane >> 4;
  const int wm = w >> 1, wn = w & 1;
  const int gx = gridDim.x;
  const int swz = xcd_swz(blockIdx.y * gx + blockIdx.x, gx * gridDim.y);
  const int m0 = (swz / gx) * 128, n0 = (swz % gx) * 128;
  v4f acc[4][4] = {};

  for (int k0 = 0; k0 < PE; k0 += 64) {
    __syncthreads();
#pragma unroll
    for (int i = 0; i < 4; ++i) {
      int idx = t + 256 * i;
      int r = idx >> 3, cs = idx & 7;
      int cg = cs ^ (r & 7);
      cp16(A + (size_t)(m0 + r) * PE + k0 + cg * 8, As + idx * 8);
      cp16(BT + (size_t)(n0 + r) * PE + k0 + cg * 8, Bs + idx * 8);
    }
    __syncthreads();
#pragma unroll
    for (int kk = 0; kk < 2; ++kk) {
      v8s af[4], bf[4];
#pragma unroll
      for (int mb = 0; mb < 4; ++mb) {
        int ra = wm * 64 + mb * 16 + ln;
        int ca = (kk * 4 + qd) ^ (ra & 7);
        af[mb] = *reinterpret_cast<const v8s*>(As + ra * 64 + ca * 8);
      }
#pragma unroll
      for (int nb = 0; nb < 4; ++nb) {
        int rb = wn * 64 + nb * 16 + ln;
        int cb = (kk * 4 + qd) ^ (rb & 7);
        bf[nb] = *reinterpret_cast<const v8s*>(Bs + rb * 64 + cb * 8);
      }
#pragma unroll
      for (int mb = 0; mb < 4; ++mb)
#pragma unroll
        for (int nb = 0; nb < 4; ++nb)
          acc[mb][nb] = __builtin_amdgcn_mfma_f32_16x16x32_bf16(af[mb], bf[nb],
                                                                acc[mb][nb], 0, 0, 0);
    }
  }

  const int mwb = m0 + wm * 64 + qd * 4;
  const int nwb = n0 + wn * 64 + ln;
  if (MODE == 0) {
    __hip_bfloat16* QKV = (__hip_bfloat16*)outv;
#pragma unroll
    for (int nb = 0; nb < 4; ++nb) {
      int n = nwb + nb * 16;
      float bv = bias[n];
      int which = n >> 10, h = (n >> 6) & 15, d = n & 63;
#pragma unroll
      for (int mb = 0; mb < 4; ++mb) {
        int r0 = mwb + mb * 16;
        int b = r0 >> 11, s0 = r0 & (PS - 1);
        v4f a = acc[mb][nb];
        if (which == 2) {
          union { ushort u[4]; uint2 v; } pk;
#pragma unroll
          for (int i = 0; i < 4; ++i) pk.u[i] = f2b(a[i] + bv);
          size_t idx = (((size_t)(2 * PB + b) * PH + h) * PD + d) * PS + s0;
          *reinterpret_cast<uint2*>(&QKV[idx]) = pk.v;
        } else {
          float sc = (which == 0) ? QSCALE : 1.0f;
          size_t base = (((size_t)(which * PB + b) * PH + h) * PS + s0) * PD + d;
#pragma unroll
          for (int i = 0; i < 4; ++i)
            QKV[base + (size_t)i * PD] = __float2bfloat16((a[i] + bv) * sc);
        }
      }
    }
  } else {
    float* Co = (float*)outv;
#pragma unroll
    for (int nb = 0; nb < 4; ++nb) {
      int n = nwb + nb * 16;
      float bv = bias[n];
#pragma unroll
      for (int mb = 0; mb < 4; ++mb) {
        int r0 = mwb + mb * 16;
        v4f a = acc[mb][nb];
#pragma unroll
        for (int i = 0; i < 4; ++i)
          Co[(size_t)(r0 + i) * PE + n] = a[i] + bv;
      }
    }
  }
}

// ---------------------------------------------------------------------------
// MFMA flash attention v8 (best verified: 106us @ R7). Register-resident P,
// T14 reg-staged K/V, XCD swizzle, XOR-swizzled 16KB LDS.
// QKV bf16: Q/K [b,h,s,d], V [b,h,d,s]. O bf16 [b,s,h,d]. Q pre-scaled.
// ---------------------------------------------------------------------------
__global__ __launch_bounds__(256) void attn_mfma8(
    const __hip_bfloat16* __restrict__ QKV, __hip_bfloat16* __restrict__ O) {
  __shared__ __hip_bfloat16 Ks[64 * 64];   // [key][d], XOR-swizzled 16B chunks
  __shared__ __hip_bfloat16 Vts[64 * 64];  // [d][key], XOR-swizzled 16B chunks
  const int t = threadIdx.x;
  const int lane = t & 63, w = t >> 6;
  const int ln = lane & 15, qd = lane >> 4;
  const int swz = xcd_swz(blockIdx.y * 16 + blockIdx.x, 16 * 64);
  const int bx = swz & 15, by = swz >> 4;
  const int b = by >> 4, h = by & 15;
  const int q0 = bx * 128;
  const __hip_bfloat16* Qb = QKV + (size_t)(b * PH + h) * PS * PD;
  const __hip_bfloat16* Kb = QKV + (size_t)((PB + b) * PH + h) * PS * PD;
  const __hip_bfloat16* Vb = QKV + (size_t)((2 * PB + b) * PH + h) * PD * PS;

  v8s qf[2][2];
#pragma unroll
  for (int u = 0; u < 2; ++u) {
    size_t qr = (size_t)(q0 + 32 * w + 16 * u + ln) * PD;
    qf[u][0] = *reinterpret_cast<const v8s*>(Qb + qr + qd * 8);
    qf[u][1] = *reinterpret_cast<const v8s*>(Qb + qr + 32 + qd * 8);
  }
  v4f oacc[2][4] = {};
  float lrow[2] = {0.f, 0.f};

  const int r7 = ln & 7;
  const int c0 = qd ^ r7;
  const int q1 = qd & 1, qh = qd >> 1;
  int soff[2][2];
#pragma unroll
  for (int s = 0; s < 2; ++s) {
    int L0 = 4 * s + qh;
    soff[s][0] = (((L0 ^ r7) << 1) | q1);
    soff[s][1] = ((((L0 + 2) ^ r7) << 1) | q1);
  }
  int rvoff[4];
#pragma unroll
  for (int db = 0; db < 4; ++db) rvoff[db] = (db * 16 + ln) * 16;

  const int sr0 = t >> 3, sc0 = t & 7;
  const int sr1 = (t + 256) >> 3, sc1 = t & 7;
  const int dk0 = sr0 * 8 + (sc0 ^ (sr0 & 7));
  const int dk1 = sr1 * 8 + (sc1 ^ (sr1 & 7));

  v8s kreg[2], vreg[2];
  auto LOADR = [&](int kt) {
    kreg[0] = *reinterpret_cast<const v8s*>(Kb + (size_t)(kt + sr0) * PD + sc0 * 8);
    vreg[0] = *reinterpret_cast<const v8s*>(Vb + (size_t)sr0 * PS + kt + sc0 * 8);
    kreg[1] = *reinterpret_cast<const v8s*>(Kb + (size_t)(kt + sr1) * PD + sc1 * 8);
    vreg[1] = *reinterpret_cast<const v8s*>(Vb + (size_t)sr1 * PS + kt + sc1 * 8);
  };
  auto DSWR = [&]() {
    *reinterpret_cast<v8s*>(Ks + dk0 * 8) = kreg[0];
    *reinterpret_cast<v8s*>(Vts + dk0 * 8) = vreg[0];
    *reinterpret_cast<v8s*>(Ks + dk1 * 8) = kreg[1];
    *reinterpret_cast<v8s*>(Vts + dk1 * 8) = vreg[1];
  };

  auto COMPUTE = [&]() {
    const __hip_bfloat16* Kbuf = Ks;
    const uint2* Vbuf = reinterpret_cast<const uint2*>(Vts);
    uint2 pw[2][4];
#pragma unroll
    for (int u = 0; u < 2; ++u) {
      float psum = 0.f;
#pragma unroll
      for (int nb = 0; nb < 4; ++nb) {
        const __hip_bfloat16* kr = Kbuf + (nb * 16 + ln) * 64;
        v8s k0 = *reinterpret_cast<const v8s*>(kr + c0 * 8);
        v8s k1 = *reinterpret_cast<const v8s*>(kr + (c0 ^ 4) * 8);
        v4f z = {};
        z = __builtin_amdgcn_mfma_f32_16x16x32_bf16(k0, qf[u][0], z, 0, 0, 0);
        v4f sv = __builtin_amdgcn_mfma_f32_16x16x32_bf16(k1, qf[u][1], z, 0, 0, 0);
        union { ushort pu[4]; uint2 pv; } pk;
#pragma unroll
        for (int i = 0; i < 4; ++i) {
          float p = fexp2(sv[i]);
          psum += p;
          pk.pu[i] = f2b(p);
        }
        pw[u][nb] = pk.pv;
      }
      psum += __shfl_xor(psum, 16);
      psum += __shfl_xor(psum, 32);
      lrow[u] += psum;
    }
#pragma unroll
    for (int s = 0; s < 2; ++s) {
      union { v8s v; uint2 u2[2]; } a0, a1;
      a0.u2[0] = pw[0][2 * s]; a0.u2[1] = pw[0][2 * s + 1];
      a1.u2[0] = pw[1][2 * s]; a1.u2[1] = pw[1][2 * s + 1];
      __builtin_amdgcn_s_setprio(1);
#pragma unroll
      for (int db = 0; db < 4; ++db) {
        union { v8s v; uint2 u2[2]; } vf;
        vf.u2[0] = Vbuf[rvoff[db] + soff[s][0]];
        vf.u2[1] = Vbuf[rvoff[db] + soff[s][1]];
        oacc[0][db] = __builtin_amdgcn_mfma_f32_16x16x32_bf16(a0.v, vf.v,
                                                              oacc[0][db], 0, 0, 0);
        oacc[1][db] = __builtin_amdgcn_mfma_f32_16x16x32_bf16(a1.v, vf.v,
                                                              oacc[1][db], 0, 0, 0);
      }
      __builtin_amdgcn_s_setprio(0);
    }
  };

  const int NT = PS / 64;
  LOADR(0);
  DSWR();
  __syncthreads();
#pragma unroll 1
  for (int it = 0; it < NT; ++it) {
    if (it + 1 < NT) LOADR((it + 1) * 64);
    COMPUTE();
    __syncthreads();
    if (it + 1 < NT) DSWR();
    __syncthreads();
  }

#pragma unroll
  for (int u = 0; u < 2; ++u) {
#pragma unroll
    for (int i = 0; i < 4; ++i) {
      float inv = 1.f / __shfl(lrow[u], qd * 4 + i);
      int sg = q0 + 32 * w + 16 * u + qd * 4 + i;
      size_t base = (((size_t)b * PS + sg) * PH + h) * PD;
#pragma unroll
      for (int db = 0; db < 4; ++db)
        O[base + db * 16 + ln] = __float2bfloat16(oacc[u][db][i] * inv);
    }
  }
}

// ---------------------------------------------------------------------------
// Legacy fp32-input GEMM (small-ws fallback)
// ---------------------------------------------------------------------------
__device__ __forceinline__ uint2 load4bf(const float* p) {
  const float4 f = *reinterpret_cast<const float4*>(p);
  union { ushort u[4]; uint2 v; } pk;
  pk.u[0] = f2b(f.x); pk.u[1] = f2b(f.y); pk.u[2] = f2b(f.z); pk.u[3] = f2b(f.w);
  return pk.v;
}
__device__ __forceinline__ uint2 load4bf(const __hip_bfloat16* p) {
  return *reinterpret_cast<const uint2*>(p);
}

template <typename AT, int MODE>
__global__ __launch_bounds__(256) void gemm128(
    const AT* __restrict__ A, const float* __restrict__ Bm,
    const float* __restrict__ bias, void* __restrict__ outv, int ldb) {
  __shared__ __hip_bfloat16 As[128][40];
  __shared__ __hip_bfloat16 Bs[128][40];
  const int t = threadIdx.x;
  const int lane = t & 63, w = t >> 6;
  const int ln = lane & 15, qd = lane >> 4;
  const int wm = w >> 1, wn = w & 1;
  const int m0 = blockIdx.y * 128, n0 = blockIdx.x * 128;
  v4f acc[4][4] = {};
  for (int k0 = 0; k0 < PE; k0 += 32) {
    __syncthreads();
#pragma unroll
    for (int i = 0; i < 4; ++i) {
      int p = t + 256 * i;
      int m = p >> 3, kc = p & 7;
      *reinterpret_cast<uint2*>(&As[m][kc * 4]) =
          load4bf(A + (size_t)(m0 + m) * PE + k0 + kc * 4);
    }
#pragma unroll
    for (int i = 0; i < 4; ++i) {
      int p = t + 256 * i;
      int n = p & 127, kc = p >> 7;
      union { ushort u[4]; uint2 v; } pk;
#pragma unroll
      for (int r = 0; r < 4; ++r)
        pk.u[r] = f2b(Bm[(size_t)(k0 + kc * 4 + r) * ldb + n0 + n]);
      *reinterpret_cast<uint2*>(&Bs[n][kc * 4]) = pk.v;
    }
    __syncthreads();
    v8s af[4], bf[4];
#pragma unroll
    for (int mb = 0; mb < 4; ++mb)
      af[mb] = *reinterpret_cast<const v8s*>(&As[wm * 64 + mb * 16 + ln][qd * 8]);
#pragma unroll
    for (int nb = 0; nb < 4; ++nb)
      bf[nb] = *reinterpret_cast<const v8s*>(&Bs[wn * 64 + nb * 16 + ln][qd * 8]);
#pragma unroll
    for (int mb = 0; mb < 4; ++mb)
#pragma unroll
      for (int nb = 0; nb < 4; ++nb)
        acc[mb][nb] = __builtin_amdgcn_mfma_f32_16x16x32_bf16(af[mb], bf[nb],
                                                              acc[mb][nb], 0, 0, 0);
  }
  const int mwb = m0 + wm * 64 + qd * 4;
  const int nwb = n0 + wn * 64 + ln;
  if (MODE == 0) {
    __hip_bfloat16* QKV = (__hip_bfloat16*)outv;
#pragma unroll
    for (int nb = 0; nb < 4; ++nb) {
      int n = nwb + nb * 16;
      float bv = bias[n];
      int which = n >> 10, h = (n >> 6) & 15, d = n & 63;
#pragma unroll
      for (int mb = 0; mb < 4; ++mb) {
        int r0 = mwb + mb * 16;
        int b = r0 >> 11, s0 = r0 & (PS - 1);
        v4f a = acc[mb][nb];
        if (which == 2) {
          union { ushort u[4]; uint2 v; } pk;
#pragma unroll
          for (int i = 0; i < 4; ++i) pk.u[i] = f2b(a[i] + bv);
          size_t idx = (((size_t)(2 * PB + b) * PH + h) * PD + d) * PS + s0;
          *reinterpret_cast<uint2*>(&QKV[idx]) = pk.v;
        } else {
          float sc = (which == 0) ? QSCALE : 1.0f;
          size_t base = (((size_t)(which * PB + b) * PH + h) * PS + s0) * PD + d;
#pragma unroll
          for (int i = 0; i < 4; ++i)
            QKV[base + (size_t)i * PD] = __float2bfloat16((a[i] + bv) * sc);
        }
      }
    }
  } else {
    float* Co = (float*)outv;
#pragma unroll
    for (int nb = 0; nb < 4; ++nb) {
      int n = nwb + nb * 16;
      float bv = bias[n];
#pragma unroll
      for (int mb = 0; mb < 4; ++mb) {
        int r0 = mwb + mb * 16;
        v4f a = acc[mb][nb];
#pragma unroll
        for (int i = 0; i < 4; ++i)
          Co[(size_t)(r0 + i) * PE + n] = a[i] + bv;
      }
    }
  }
}

// ---------------------------------------------------------------------------
extern "C" void kernel_launch(void* const* d_in, const int* in_sizes, int n_in,
                              void* d_out, int out_size, void* d_ws,
                              size_t ws_size, hipStream_t stream) {
  const float* x = (const float*)d_in[0];
  const float* w_qkv = (const float*)d_in[1];
  const float* b_qkv = (const float*)d_in[2];
  const float* w_proj = (const float*)d_in[3];
  const float* b_proj = (const float*)d_in[4];
  float* out = (float*)d_out;

  const size_t xE = (size_t)PB * PS * PE;             // 8,388,608
  const size_t wqE = (size_t)PE * 3 * PE;             // 3,145,728
  const size_t wpE = (size_t)PE * PE;                 // 1,048,576
  const size_t qkvE = (size_t)3 * PB * PH * PS * PD;  // 25,165,824
  const size_t needMain = (xE + wqE + wpE + qkvE) * 2;  // 75,497,472 B

  dim3 blk(256);
  dim3 gq256(12, 32), ga(16, 64), gp(8, 64);
  dim3 gq(24, 64);

  if (ws_size >= needMain) {
    __hip_bfloat16* xb = (__hip_bfloat16*)d_ws;
    __hip_bfloat16* wqkvT = xb + xE;
    __hip_bfloat16* wprojT = wqkvT + wqE;
    __hip_bfloat16* qkv = wprojT + wpE;
    __hip_bfloat16* o = xb;  // xb dead after qkv gemm

    conv_f2b<<<dim3(xE / 1024), blk, 0, stream>>>(x, xb);
    transp_f2b<<<dim3(96, 32), blk, 0, stream>>>(w_qkv, wqkvT, PE, 3 * PE);
    transp_f2b<<<dim3(32, 32), blk, 0, stream>>>(w_proj, wprojT, PE, PE);
    gemm256<<<gq256, dim3(512), 0, stream>>>(xb, wqkvT, b_qkv, qkv);
    attn_mfma8<<<ga, blk, 0, stream>>>(qkv, o);
    gemm_bt<1><<<gp, blk, 0, stream>>>(o, wprojT, b_proj, out);
  } else {
    // legacy small-ws path
    __hip_bfloat16* qkv = (__hip_bfloat16*)d_ws;
    if (ws_size >= (qkvE + xE) * 2) {
      __hip_bfloat16* o = qkv + qkvE;
      gemm128<float, 0><<<gq, blk, 0, stream>>>(x, w_qkv, b_qkv, qkv, 3 * PE);
      attn_mfma8<<<ga, blk, 0, stream>>>(qkv, o);
      gemm128<__hip_bfloat16, 1><<<gp, blk, 0, stream>>>(o, w_proj, b_proj, out, PE);
    } else {
      __hip_bfloat16* o = (__hip_bfloat16*)d_out;
      float* tmp = (float*)d_ws;
      gemm128<float, 0><<<gq, blk, 0, stream>>>(x, w_qkv, b_qkv, qkv, 3 * PE);
      attn_mfma8<<<ga, blk, 0, stream>>>(qkv, o);
      gemm128<__hip_bfloat16, 1><<<gp, blk, 0, stream>>>(o, w_proj, b_proj, tmp, PE);
      hipMemcpyAsync(d_out, tmp, xE * sizeof(float), hipMemcpyDeviceToDevice, stream);
    }
  }
}

// Round 12
// 289.923 us; speedup vs baseline: 1.8221x; 1.0227x over previous
//
#include <hip/hip_runtime.h>
#include <hip/hip_bf16.h>

// B=4, S=2048, E=1024, H=16, D=64
#define PB 4
#define PS 2048
#define PH 16
#define PD 64
#define PE 1024

typedef short v8s __attribute__((ext_vector_type(8)));
typedef float v4f __attribute__((ext_vector_type(4)));

// Q pre-scale: 1/sqrt(D) * log2(e), so softmax exp() becomes exp2()
#define QSCALE 0.18033688f

__device__ __forceinline__ ushort f2b(float f) {
  union { __hip_bfloat16 b; ushort u; } cv;
  cv.b = __float2bfloat16(f);
  return cv.u;
}

#if __has_builtin(__builtin_amdgcn_exp2f)
__device__ __forceinline__ float fexp2(float x) { return __builtin_amdgcn_exp2f(x); }
#else
__device__ __forceinline__ float fexp2(float x) { return exp2f(x); }
#endif

// async 16B global->LDS (direct DMA, no VGPR round trip) — used by GEMMs
__device__ __forceinline__ void cp16(const __hip_bfloat16* g, __hip_bfloat16* l) {
  __builtin_amdgcn_global_load_lds(
      (const __attribute__((address_space(1))) void*)g,
      (__attribute__((address_space(3))) void*)l, 16, 0, 0);
}

// XCD-aware bijective block remap (T1, verified R7: attn FETCH 139->24MB).
// Requires nwg % 8 == 0 (grids: 1024 / 1536 / 512).
__device__ __forceinline__ int xcd_swz(int orig, int nwg) {
  return (orig & 7) * (nwg >> 3) + (orig >> 3);
}

// ---------------------------------------------------------------------------
// Prep kernels: fp32 -> bf16 convert / transpose (memory-bound)
// ---------------------------------------------------------------------------
__global__ __launch_bounds__(256) void conv_f2b(const float* __restrict__ S,
                                                __hip_bfloat16* __restrict__ D) {
  int i = blockIdx.x * 256 + threadIdx.x;
  float4 f = reinterpret_cast<const float4*>(S)[i];
  union { ushort u[4]; uint2 v; } pk;
  pk.u[0] = f2b(f.x); pk.u[1] = f2b(f.y); pk.u[2] = f2b(f.z); pk.u[3] = f2b(f.w);
  reinterpret_cast<uint2*>(D)[i] = pk.v;
}

// S [R][C] fp32 -> D [C][R] bf16
__global__ __launch_bounds__(256) void transp_f2b(const float* __restrict__ S,
                                                  __hip_bfloat16* __restrict__ D,
                                                  int R, int C) {
  __shared__ float tile[32][33];
  const int t = threadIdx.x;
  const int tx = t & 31, ty = t >> 5;
  const int r0 = blockIdx.y * 32, c0 = blockIdx.x * 32;
#pragma unroll
  for (int i = 0; i < 4; ++i)
    tile[ty + 8 * i][tx] = S[(size_t)(r0 + ty + 8 * i) * C + c0 + tx];
  __syncthreads();
#pragma unroll
  for (int i = 0; i < 4; ++i)
    D[(size_t)(c0 + ty + 8 * i) * R + r0 + tx] = __float2bfloat16(tile[tx][ty + 8 * i]);
}

// ---------------------------------------------------------------------------
// MFMA GEMM 128x128, BK=64, XOR-swizzled LDS, global_load_lds staging.
// MODE 0: QKV scatter epilogue; MODE 1: proj fp32 epilogue. XCD-swizzled.
// (R10 lesson: 256-tile 8-phase port regressed — 384 tiles = 1.5 dispatch
// rounds at 1 block/CU; 128-tile with 1536 blocks is load-balanced and at
// its structural ceiling. Keep it.)
// ---------------------------------------------------------------------------
template <int MODE>
__global__ __launch_bounds__(256) void gemm_bt(
    const __hip_bfloat16* __restrict__ A, const __hip_bfloat16* __restrict__ BT,
    const float* __restrict__ bias, void* __restrict__ outv) {
  __shared__ __hip_bfloat16 As[128 * 64];
  __shared__ __hip_bfloat16 Bs[128 * 64];
  const int t = threadIdx.x;
  const int lane = t & 63, w = t >> 6;
  const int ln = lane & 15, qd = lane >> 4;
  const int wm = w >> 1, wn = w & 1;
  const int gx = gridDim.x;
  const int swz = xcd_swz(blockIdx.y * gx + blockIdx.x, gx * gridDim.y);
  const int m0 = (swz / gx) * 128, n0 = (swz % gx) * 128;
  v4f acc[4][4] = {};

  for (int k0 = 0; k0 < PE; k0 += 64) {
    __syncthreads();
#pragma unroll
    for (int i = 0; i < 4; ++i) {
      int idx = t + 256 * i;           // 0..1023 16B slots
      int r = idx >> 3, cs = idx & 7;  // 8 chunks per 64-elem row
      int cg = cs ^ (r & 7);
      cp16(A + (size_t)(m0 + r) * PE + k0 + cg * 8, As + idx * 8);
      cp16(BT + (size_t)(n0 + r) * PE + k0 + cg * 8, Bs + idx * 8);
    }
    __syncthreads();
#pragma unroll
    for (int kk = 0; kk < 2; ++kk) {
      v8s af[4], bf[4];
#pragma unroll
      for (int mb = 0; mb < 4; ++mb) {
        int ra = wm * 64 + mb * 16 + ln;
        int ca = (kk * 4 + qd) ^ (ra & 7);
        af[mb] = *reinterpret_cast<const v8s*>(As + ra * 64 + ca * 8);
      }
#pragma unroll
      for (int nb = 0; nb < 4; ++nb) {
        int rb = wn * 64 + nb * 16 + ln;
        int cb = (kk * 4 + qd) ^ (rb & 7);
        bf[nb] = *reinterpret_cast<const v8s*>(Bs + rb * 64 + cb * 8);
      }
#pragma unroll
      for (int mb = 0; mb < 4; ++mb)
#pragma unroll
        for (int nb = 0; nb < 4; ++nb)
          acc[mb][nb] = __builtin_amdgcn_mfma_f32_16x16x32_bf16(af[mb], bf[nb],
                                                                acc[mb][nb], 0, 0, 0);
    }
  }

  const int mwb = m0 + wm * 64 + qd * 4;
  const int nwb = n0 + wn * 64 + ln;
  if (MODE == 0) {
    __hip_bfloat16* QKV = (__hip_bfloat16*)outv;
#pragma unroll
    for (int nb = 0; nb < 4; ++nb) {
      int n = nwb + nb * 16;
      float bv = bias[n];
      int which = n >> 10, h = (n >> 6) & 15, d = n & 63;
#pragma unroll
      for (int mb = 0; mb < 4; ++mb) {
        int r0 = mwb + mb * 16;
        int b = r0 >> 11, s0 = r0 & (PS - 1);
        v4f a = acc[mb][nb];
        if (which == 2) {
          union { ushort u[4]; uint2 v; } pk;
#pragma unroll
          for (int i = 0; i < 4; ++i) pk.u[i] = f2b(a[i] + bv);
          size_t idx = (((size_t)(2 * PB + b) * PH + h) * PD + d) * PS + s0;
          *reinterpret_cast<uint2*>(&QKV[idx]) = pk.v;
        } else {
          float sc = (which == 0) ? QSCALE : 1.0f;
          size_t base = (((size_t)(which * PB + b) * PH + h) * PS + s0) * PD + d;
#pragma unroll
          for (int i = 0; i < 4; ++i)
            QKV[base + (size_t)i * PD] = __float2bfloat16((a[i] + bv) * sc);
        }
      }
    }
  } else {
    float* Co = (float*)outv;
#pragma unroll
    for (int nb = 0; nb < 4; ++nb) {
      int n = nwb + nb * 16;
      float bv = bias[n];
#pragma unroll
      for (int mb = 0; mb < 4; ++mb) {
        int r0 = mwb + mb * 16;
        v4f a = acc[mb][nb];
#pragma unroll
        for (int i = 0; i < 4; ++i)
          Co[(size_t)(r0 + i) * PE + n] = a[i] + bv;
      }
    }
  }
}

// ---------------------------------------------------------------------------
// MFMA flash attention v13 = v8 (best verified) + double-buffered K/V and
// ONE barrier per tile (v8 had two). Region it:
//   { LOADR(it+1)->regs ; COMPUTE(buf=it&1) ; DSWR(buf=(it+1)&1) ; barrier }
// RAW: writes to buf^1 are barriered before region it+1 reads them.
// WAR: buf^1 was last read in COMPUTE(it-1), already ordered by the barrier
// at the end of region it-1 — so writing it in region it is safe.
// Register-resident P, T14 reg-staging, XCD swizzle, XOR-swizzled LDS.
// QKV bf16: Q/K [b,h,s,d], V [b,h,d,s]. O bf16 [b,s,h,d]. Q pre-scaled.
// ---------------------------------------------------------------------------
__global__ __launch_bounds__(256) void attn_mfma13(
    const __hip_bfloat16* __restrict__ QKV, __hip_bfloat16* __restrict__ O) {
  __shared__ __hip_bfloat16 Ks[2][64 * 64];   // [key][d], XOR-swizzled chunks
  __shared__ __hip_bfloat16 Vts[2][64 * 64];  // [d][key], XOR-swizzled chunks
  const int t = threadIdx.x;
  const int lane = t & 63, w = t >> 6;
  const int ln = lane & 15, qd = lane >> 4;
  const int swz = xcd_swz(blockIdx.y * 16 + blockIdx.x, 16 * 64);
  const int bx = swz & 15, by = swz >> 4;
  const int b = by >> 4, h = by & 15;
  const int q0 = bx * 128;
  const __hip_bfloat16* Qb = QKV + (size_t)(b * PH + h) * PS * PD;
  const __hip_bfloat16* Kb = QKV + (size_t)((PB + b) * PH + h) * PS * PD;
  const __hip_bfloat16* Vb = QKV + (size_t)((2 * PB + b) * PH + h) * PD * PS;

  // Q B-frags: wave w owns q-rows q0+32w .. +31 (two 16-row sub-blocks u)
  v8s qf[2][2];
#pragma unroll
  for (int u = 0; u < 2; ++u) {
    size_t qr = (size_t)(q0 + 32 * w + 16 * u + ln) * PD;
    qf[u][0] = *reinterpret_cast<const v8s*>(Qb + qr + qd * 8);
    qf[u][1] = *reinterpret_cast<const v8s*>(Qb + qr + 32 + qd * 8);
  }
  v4f oacc[2][4] = {};
  float lrow[2] = {0.f, 0.f};

  // kt-invariant LDS read address components
  const int r7 = ln & 7;
  const int c0 = qd ^ r7;  // K 16B-slot base (second read: c0^4)
  const int q1 = qd & 1, qh = qd >> 1;
  int soff[2][2];  // V 8B-slot offsets per k-slice s (uint2 units)
#pragma unroll
  for (int s = 0; s < 2; ++s) {
    int L0 = 4 * s + qh;
    soff[s][0] = (((L0 ^ r7) << 1) | q1);
    soff[s][1] = ((((L0 + 2) ^ r7) << 1) | q1);
  }
  int rvoff[4];  // V row offsets (uint2 units; row = 64 bf16 = 16 uint2)
#pragma unroll
  for (int db = 0; db < 4; ++db) rvoff[db] = (db * 16 + ln) * 16;

  // per-thread staging geometry (kt-invariant): 2 K chunks + 2 V chunks
  // global source LINEAR (coalesced); LDS dest slot XOR-swizzled.
  const int sr0 = t >> 3, sc0 = t & 7;            // idx = t
  const int sr1 = (t + 256) >> 3, sc1 = t & 7;    // idx = t+256
  const int dk0 = sr0 * 8 + (sc0 ^ (sr0 & 7));
  const int dk1 = sr1 * 8 + (sc1 ^ (sr1 & 7));

  v8s kreg[2], vreg[2];
  auto LOADR = [&](int kt) {
    kreg[0] = *reinterpret_cast<const v8s*>(Kb + (size_t)(kt + sr0) * PD + sc0 * 8);
    vreg[0] = *reinterpret_cast<const v8s*>(Vb + (size_t)sr0 * PS + kt + sc0 * 8);
    kreg[1] = *reinterpret_cast<const v8s*>(Kb + (size_t)(kt + sr1) * PD + sc1 * 8);
    vreg[1] = *reinterpret_cast<const v8s*>(Vb + (size_t)sr1 * PS + kt + sc1 * 8);
  };
  auto DSWR = [&](int hf) {
    *reinterpret_cast<v8s*>(Ks[hf] + dk0 * 8) = kreg[0];
    *reinterpret_cast<v8s*>(Vts[hf] + dk0 * 8) = vreg[0];
    *reinterpret_cast<v8s*>(Ks[hf] + dk1 * 8) = kreg[1];
    *reinterpret_cast<v8s*>(Vts[hf] + dk1 * 8) = vreg[1];
  };

  auto COMPUTE = [&](int hf) {
    const __hip_bfloat16* Kbuf = Ks[hf];
    const uint2* Vbuf = reinterpret_cast<const uint2*>(Vts[hf]);
    // S^T = K Q^T per sub-block; exp2; pack P into registers (pw)
    uint2 pw[2][4];
#pragma unroll
    for (int u = 0; u < 2; ++u) {
      float psum = 0.f;
#pragma unroll
      for (int nb = 0; nb < 4; ++nb) {
        const __hip_bfloat16* kr = Kbuf + (nb * 16 + ln) * 64;
        v8s k0 = *reinterpret_cast<const v8s*>(kr + c0 * 8);
        v8s k1 = *reinterpret_cast<const v8s*>(kr + (c0 ^ 4) * 8);
        v4f z = {};
        z = __builtin_amdgcn_mfma_f32_16x16x32_bf16(k0, qf[u][0], z, 0, 0, 0);
        v4f sv = __builtin_amdgcn_mfma_f32_16x16x32_bf16(k1, qf[u][1], z, 0, 0, 0);
        // lane holds keys nb*16+qd*4+i of q = 32w+16u+ln
        union { ushort pu[4]; uint2 pv; } pk;
#pragma unroll
        for (int i = 0; i < 4; ++i) {
          float p = fexp2(sv[i]);
          psum += p;
          pk.pu[i] = f2b(p);
        }
        pw[u][nb] = pk.pv;
      }
      // reduce over qd lane-groups (lane bits 4,5)
      psum += __shfl_xor(psum, 16);
      psum += __shfl_xor(psum, 32);
      lrow[u] += psum;
    }
    // O += P V, P direct from registers with permuted key order.
    // Slice s covers keys [32s,32s+32): A = concat(pw[2s], pw[2s+1]);
    // k-slot qd*8+j <-> key (2s+(j>>2))*16 + qd*4 + (j&3), matched on V.
#pragma unroll
    for (int s = 0; s < 2; ++s) {
      union { v8s v; uint2 u2[2]; } a0, a1;
      a0.u2[0] = pw[0][2 * s]; a0.u2[1] = pw[0][2 * s + 1];
      a1.u2[0] = pw[1][2 * s]; a1.u2[1] = pw[1][2 * s + 1];
      __builtin_amdgcn_s_setprio(1);
#pragma unroll
      for (int db = 0; db < 4; ++db) {
        union { v8s v; uint2 u2[2]; } vf;
        vf.u2[0] = Vbuf[rvoff[db] + soff[s][0]];
        vf.u2[1] = Vbuf[rvoff[db] + soff[s][1]];
        oacc[0][db] = __builtin_amdgcn_mfma_f32_16x16x32_bf16(a0.v, vf.v,
                                                              oacc[0][db], 0, 0, 0);
        oacc[1][db] = __builtin_amdgcn_mfma_f32_16x16x32_bf16(a1.v, vf.v,
                                                              oacc[1][db], 0, 0, 0);
      }
      __builtin_amdgcn_s_setprio(0);
    }
  };

  // Double-buffered loop, ONE barrier per tile.
  const int NT = PS / 64;  // 32
  LOADR(0);
  DSWR(0);
  __syncthreads();
#pragma unroll 1
  for (int it = 0; it < NT; ++it) {
    if (it + 1 < NT) LOADR((it + 1) * 64);
    COMPUTE(it & 1);
    if (it + 1 < NT) DSWR((it + 1) & 1);
    __syncthreads();
  }

  // epilogue: redistribute lrow (indexed by q=ln) to O C-layout (q=qd*4+i)
#pragma unroll
  for (int u = 0; u < 2; ++u) {
#pragma unroll
    for (int i = 0; i < 4; ++i) {
      float inv = 1.f / __shfl(lrow[u], qd * 4 + i);
      int sg = q0 + 32 * w + 16 * u + qd * 4 + i;
      size_t base = (((size_t)b * PS + sg) * PH + h) * PD;
#pragma unroll
      for (int db = 0; db < 4; ++db)
        O[base + db * 16 + ln] = __float2bfloat16(oacc[u][db][i] * inv);
    }
  }
}

// ---------------------------------------------------------------------------
// Legacy fp32-input GEMM (small-ws fallback)
// ---------------------------------------------------------------------------
__device__ __forceinline__ uint2 load4bf(const float* p) {
  const float4 f = *reinterpret_cast<const float4*>(p);
  union { ushort u[4]; uint2 v; } pk;
  pk.u[0] = f2b(f.x); pk.u[1] = f2b(f.y); pk.u[2] = f2b(f.z); pk.u[3] = f2b(f.w);
  return pk.v;
}
__device__ __forceinline__ uint2 load4bf(const __hip_bfloat16* p) {
  return *reinterpret_cast<const uint2*>(p);
}

template <typename AT, int MODE>
__global__ __launch_bounds__(256) void gemm128(
    const AT* __restrict__ A, const float* __restrict__ Bm,
    const float* __restrict__ bias, void* __restrict__ outv, int ldb) {
  __shared__ __hip_bfloat16 As[128][40];
  __shared__ __hip_bfloat16 Bs[128][40];
  const int t = threadIdx.x;
  const int lane = t & 63, w = t >> 6;
  const int ln = lane & 15, qd = lane >> 4;
  const int wm = w >> 1, wn = w & 1;
  const int m0 = blockIdx.y * 128, n0 = blockIdx.x * 128;
  v4f acc[4][4] = {};
  for (int k0 = 0; k0 < PE; k0 += 32) {
    __syncthreads();
#pragma unroll
    for (int i = 0; i < 4; ++i) {
      int p = t + 256 * i;
      int m = p >> 3, kc = p & 7;
      *reinterpret_cast<uint2*>(&As[m][kc * 4]) =
          load4bf(A + (size_t)(m0 + m) * PE + k0 + kc * 4);
    }
#pragma unroll
    for (int i = 0; i < 4; ++i) {
      int p = t + 256 * i;
      int n = p & 127, kc = p >> 7;
      union { ushort u[4]; uint2 v; } pk;
#pragma unroll
      for (int r = 0; r < 4; ++r)
        pk.u[r] = f2b(Bm[(size_t)(k0 + kc * 4 + r) * ldb + n0 + n]);
      *reinterpret_cast<uint2*>(&Bs[n][kc * 4]) = pk.v;
    }
    __syncthreads();
    v8s af[4], bf[4];
#pragma unroll
    for (int mb = 0; mb < 4; ++mb)
      af[mb] = *reinterpret_cast<const v8s*>(&As[wm * 64 + mb * 16 + ln][qd * 8]);
#pragma unroll
    for (int nb = 0; nb < 4; ++nb)
      bf[nb] = *reinterpret_cast<const v8s*>(&Bs[wn * 64 + nb * 16 + ln][qd * 8]);
#pragma unroll
    for (int mb = 0; mb < 4; ++mb)
#pragma unroll
      for (int nb = 0; nb < 4; ++nb)
        acc[mb][nb] = __builtin_amdgcn_mfma_f32_16x16x32_bf16(af[mb], bf[nb],
                                                              acc[mb][nb], 0, 0, 0);
  }
  const int mwb = m0 + wm * 64 + qd * 4;
  const int nwb = n0 + wn * 64 + ln;
  if (MODE == 0) {
    __hip_bfloat16* QKV = (__hip_bfloat16*)outv;
#pragma unroll
    for (int nb = 0; nb < 4; ++nb) {
      int n = nwb + nb * 16;
      float bv = bias[n];
      int which = n >> 10, h = (n >> 6) & 15, d = n & 63;
#pragma unroll
      for (int mb = 0; mb < 4; ++mb) {
        int r0 = mwb + mb * 16;
        int b = r0 >> 11, s0 = r0 & (PS - 1);
        v4f a = acc[mb][nb];
        if (which == 2) {
          union { ushort u[4]; uint2 v; } pk;
#pragma unroll
          for (int i = 0; i < 4; ++i) pk.u[i] = f2b(a[i] + bv);
          size_t idx = (((size_t)(2 * PB + b) * PH + h) * PD + d) * PS + s0;
          *reinterpret_cast<uint2*>(&QKV[idx]) = pk.v;
        } else {
          float sc = (which == 0) ? QSCALE : 1.0f;
          size_t base = (((size_t)(which * PB + b) * PH + h) * PS + s0) * PD + d;
#pragma unroll
          for (int i = 0; i < 4; ++i)
            QKV[base + (size_t)i * PD] = __float2bfloat16((a[i] + bv) * sc);
        }
      }
    }
  } else {
    float* Co = (float*)outv;
#pragma unroll
    for (int nb = 0; nb < 4; ++nb) {
      int n = nwb + nb * 16;
      float bv = bias[n];
#pragma unroll
      for (int mb = 0; mb < 4; ++mb) {
        int r0 = mwb + mb * 16;
        v4f a = acc[mb][nb];
#pragma unroll
        for (int i = 0; i < 4; ++i)
          Co[(size_t)(r0 + i) * PE + n] = a[i] + bv;
      }
    }
  }
}

// ---------------------------------------------------------------------------
extern "C" void kernel_launch(void* const* d_in, const int* in_sizes, int n_in,
                              void* d_out, int out_size, void* d_ws,
                              size_t ws_size, hipStream_t stream) {
  const float* x = (const float*)d_in[0];
  const float* w_qkv = (const float*)d_in[1];
  const float* b_qkv = (const float*)d_in[2];
  const float* w_proj = (const float*)d_in[3];
  const float* b_proj = (const float*)d_in[4];
  float* out = (float*)d_out;

  const size_t xE = (size_t)PB * PS * PE;             // 8,388,608
  const size_t wqE = (size_t)PE * 3 * PE;             // 3,145,728
  const size_t wpE = (size_t)PE * PE;                 // 1,048,576
  const size_t qkvE = (size_t)3 * PB * PH * PS * PD;  // 25,165,824
  const size_t needMain = (xE + wqE + wpE + qkvE) * 2;  // 75,497,472 B

  dim3 blk(256);
  dim3 gq(24, 64), ga(16, 64), gp(8, 64);

  if (ws_size >= needMain) {
    __hip_bfloat16* xb = (__hip_bfloat16*)d_ws;
    __hip_bfloat16* wqkvT = xb + xE;
    __hip_bfloat16* wprojT = wqkvT + wqE;
    __hip_bfloat16* qkv = wprojT + wpE;
    __hip_bfloat16* o = xb;  // xb dead after qkv gemm

    conv_f2b<<<dim3(xE / 1024), blk, 0, stream>>>(x, xb);
    transp_f2b<<<dim3(96, 32), blk, 0, stream>>>(w_qkv, wqkvT, PE, 3 * PE);
    transp_f2b<<<dim3(32, 32), blk, 0, stream>>>(w_proj, wprojT, PE, PE);
    gemm_bt<0><<<gq, blk, 0, stream>>>(xb, wqkvT, b_qkv, qkv);
    attn_mfma13<<<ga, blk, 0, stream>>>(qkv, o);
    gemm_bt<1><<<gp, blk, 0, stream>>>(o, wprojT, b_proj, out);
  } else {
    // legacy small-ws path
    __hip_bfloat16* qkv = (__hip_bfloat16*)d_ws;
    if (ws_size >= (qkvE + xE) * 2) {
      __hip_bfloat16* o = qkv + qkvE;
      gemm128<float, 0><<<gq, blk, 0, stream>>>(x, w_qkv, b_qkv, qkv, 3 * PE);
      attn_mfma13<<<ga, blk, 0, stream>>>(qkv, o);
      gemm128<__hip_bfloat16, 1><<<gp, blk, 0, stream>>>(o, w_proj, b_proj, out, PE);
    } else {
      __hip_bfloat16* o = (__hip_bfloat16*)d_out;
      float* tmp = (float*)d_ws;
      gemm128<float, 0><<<gq, blk, 0, stream>>>(x, w_qkv, b_qkv, qkv, 3 * PE);
      attn_mfma13<<<ga, blk, 0, stream>>>(qkv, o);
      gemm128<__hip_bfloat16, 1><<<gp, blk, 0, stream>>>(o, w_proj, b_proj, tmp, PE);
      hipMemcpyAsync(d_out, tmp, xE * sizeof(float), hipMemcpyDeviceToDevice, stream);
    }
  }
}